// Round 17
// baseline (99.325 us; speedup 1.0000x reference)
//
#include <hip/hip_runtime.h>
#include <hip/hip_bf16.h>

#define BTOT 4
#define NPTS 4096
#define FTOT 6
#define KNN 8
#define EPSV 1e-3f

// xor-butterfly on u64 via ds_swizzle BitMode (s<=16, within 32-lane half).
template <int P>
__device__ __forceinline__ unsigned long long swz_xor_u64(unsigned long long v) {
    unsigned lo = (unsigned)v, hi = (unsigned)(v >> 32);
    lo = (unsigned)__builtin_amdgcn_ds_swizzle((int)lo, P);
    hi = (unsigned)__builtin_amdgcn_ds_swizzle((int)hi, P);
    return ((unsigned long long)hi << 32) | lo;
}
// cross-half step (lane ^ 32) via full-wave shfl_xor.
__device__ __forceinline__ unsigned long long shfl32_u64(unsigned long long v) {
    unsigned lo = (unsigned)v, hi = (unsigned)(v >> 32);
    lo = (unsigned)__shfl_xor((int)lo, 32);
    hi = (unsigned)__shfl_xor((int)hi, 32);
    return ((unsigned long long)hi << 32) | lo;
}
#define MERGE_STEP(P) { unsigned long long o_ = swz_xor_u64<P>(mn); mn = (o_ < mn) ? o_ : mn; }
#define MERGE_MIN_U64_64() \
    MERGE_STEP(0x041F) MERGE_STEP(0x081F) MERGE_STEP(0x101F) MERGE_STEP(0x201F) MERGE_STEP(0x401F) \
    { unsigned long long o_ = shfl32_u64(mn); mn = (o_ < mn) ? o_ : mn; }

// ---------------- bn1: identical to round 16 (passed) ----------------
__global__ __launch_bounds__(256) void k_bn1(const float* __restrict__ in,
                                             const float* __restrict__ g,
                                             const float* __restrict__ b,
                                             const float* __restrict__ m,
                                             const float* __restrict__ v,
                                             float* __restrict__ x,
                                             float2* __restrict__ pos) {
    int i = blockIdx.x * 256 + threadIdx.x;
    if (i >= BTOT * NPTS) return;
    float o[FTOT];
#pragma unroll
    for (int f = 0; f < FTOT; ++f) {
        float val = in[(size_t)i * FTOT + f];
        o[f] = (val - m[f]) * rsqrtf(v[f] + EPSV) * g[f] + b[f];
        x[(size_t)i * FTOT + f] = o[f];
    }
    pos[i] = make_float2(o[0], o[1]);
}

// ---------------- KNN v9: FROZEN v6s selection math, repartitioned to 64 lanes/query.
// u64 keys everywhere, single-level insert, sentinel init, 9-round extraction, clamp.
// Output identical to v6s: unique keys => extracted global top-9 independent of partitioning. ----------------
__global__ __launch_bounds__(512) void k_knn(const float2* __restrict__ posg,
                                             int* __restrict__ idx) {
    __shared__ float2 spos[NPTS];  // 32 KB
    int b  = blockIdx.x >> 9;                 // 512 blocks per batch
    int q0 = (blockIdx.x & 511) << 3;         // 8 queries per block
    int t  = threadIdx.x;
    const float2* pb = posg + (size_t)b * NPTS;
    for (int j = t; j < NPTS; j += 512) spos[j] = pb[j];
    __syncthreads();

    int lq = t >> 6;          // local query 0..7
    int p  = t & 63;          // partition lane 0..63 (full wave per query)
    int qq = q0 + lq;
    float2 q = spos[qq];

    // ---- pass 1: per-lane lexicographic-min u64 key, 4 independent accumulators ----
    unsigned long long bm0 = ~0ULL, bm1 = ~0ULL, bm2 = ~0ULL, bm3 = ~0ULL;
    for (int jj = 0; jj < NPTS / 64; jj += 4) {
        int j0 = ((jj + 0) << 6) + p;
        int j1 = ((jj + 1) << 6) + p;
        int j2 = ((jj + 2) << 6) + p;
        int j3 = ((jj + 3) << 6) + p;
        float2 p0 = spos[j0], p1 = spos[j1], p2 = spos[j2], p3 = spos[j3];
        float d0 = __fadd_rn(__fmul_rn(q.x - p0.x, q.x - p0.x), __fmul_rn(q.y - p0.y, q.y - p0.y));
        float d1 = __fadd_rn(__fmul_rn(q.x - p1.x, q.x - p1.x), __fmul_rn(q.y - p1.y, q.y - p1.y));
        float d2 = __fadd_rn(__fmul_rn(q.x - p2.x, q.x - p2.x), __fmul_rn(q.y - p2.y, q.y - p2.y));
        float d3 = __fadd_rn(__fmul_rn(q.x - p3.x, q.x - p3.x), __fmul_rn(q.y - p3.y, q.y - p3.y));
        unsigned long long k0 = ((unsigned long long)__float_as_uint(d0) << 32) | (unsigned)j0;
        unsigned long long k1 = ((unsigned long long)__float_as_uint(d1) << 32) | (unsigned)j1;
        unsigned long long k2 = ((unsigned long long)__float_as_uint(d2) << 32) | (unsigned)j2;
        unsigned long long k3 = ((unsigned long long)__float_as_uint(d3) << 32) | (unsigned)j3;
        bm0 = k0 < bm0 ? k0 : bm0;
        bm1 = k1 < bm1 ? k1 : bm1;
        bm2 = k2 < bm2 ? k2 : bm2;
        bm3 = k3 < bm3 ? k3 : bm3;
    }
    unsigned long long bma = bm0 < bm1 ? bm0 : bm1;
    unsigned long long bmb = bm2 < bm3 ? bm2 : bm3;
    unsigned long long bm  = bma < bmb ? bma : bmb;

    // ---- threshold r = 9th smallest of the 64 lane-min keys ----
    unsigned long long KK = bm, r = 0;
#pragma unroll
    for (int rd = 0; rd < 9; ++rd) {
        unsigned long long mn = KK;
        MERGE_MIN_U64_64()
        if (KK == mn) KK = ~0ULL;   // owner retires (keys unique)
        r = mn;
    }
    unsigned long long sent = r + 1;  // keys unique: key <= r  <=>  key < sent

    // ---- pass 2: per-lane top-9 insertion, single-level if (required structure) ----
    unsigned long long K[9];
#pragma unroll
    for (int m = 0; m < 9; ++m) K[m] = sent;

#pragma unroll 4
    for (int jj = 0; jj < NPTS / 64; ++jj) {
        int j = (jj << 6) + p;
        float2 pt = spos[j];
        float dx = q.x - pt.x;
        float dy = q.y - pt.y;
        float d2 = __fadd_rn(__fmul_rn(dx, dx), __fmul_rn(dy, dy));  // no FMA contraction
        unsigned long long key = ((unsigned long long)__float_as_uint(d2) << 32) | (unsigned)j;
        if (key < K[8]) {
            K[8] = key;
#pragma unroll
            for (int m = 8; m > 0; --m) {
                bool sw = K[m] < K[m - 1];
                unsigned long long a = sw ? K[m - 1] : K[m];
                unsigned long long c = sw ? K[m] : K[m - 1];
                K[m] = a; K[m - 1] = c;
            }
        }
    }

    // ---- 9 extraction rounds: global min over the 64-lane wave (>=9 real keys < sent) ----
    int rec = qq;   // inert when correct; keeps downstream in-range if not
#pragma unroll
    for (int rd = 0; rd < 9; ++rd) {
        unsigned long long mn = K[0];
        MERGE_MIN_U64_64()
        if (K[0] == mn) {   // this lane owned the min: advance its sorted list
#pragma unroll
            for (int i = 0; i < 8; ++i) K[i] = K[i + 1];
            K[8] = ~0ULL;
        }
        if (rd >= 1 && p == rd - 1) rec = (int)(unsigned)mn;   // rounds 1..8 = the 8 neighbors
    }
    rec &= (NPTS - 1);   // hard-mask to [0,4096): downstream gathers can never fault
    if (p < 8)
        idx[((size_t)b * NPTS + qq) * KNN + p] = rec;
}

// ---------------- gravnet1 v2: identical to round 16 (passed) ----------------
__global__ __launch_bounds__(256) void k_g1(const float* __restrict__ x,
                                            const int* __restrict__ idx,
                                            const float* __restrict__ w1,
                                            const float* __restrict__ b1,
                                            const float* __restrict__ w2,
                                            const float* __restrict__ b2,
                                            float* __restrict__ xcat) {
    __shared__ float sw1[4 * 33], sw2[32 * 33], sb1[32], sb2[32];
    int t = threadIdx.x;
    if (t < 128) sw1[(t >> 5) * 33 + (t & 31)] = w1[t];
    for (int u = t; u < 1024; u += 256) sw2[(u >> 5) * 33 + (u & 31)] = w2[u];
    if (t < 32) { sb1[t] = b1[t]; sb2[t] = b2[t]; }
    __syncthreads();

    int i = blockIdx.x * 64 + (t >> 2);   // point
    int s = t & 3;                        // sublane
    int qb = (t & 63) & ~3;               // quad base lane within wave
    int b = i >> 12;
    int n = i & (NPTS - 1);
    const float* xb = x + (size_t)b * NPTS * FTOT;

    float aggs = 0.f;
#pragma unroll
    for (int k = 0; k < KNN; ++k) {
        int nb = idx[(size_t)i * KNN + k];
        aggs += xb[(size_t)nb * FTOT + 2 + s];
    }
    aggs *= 0.125f;

    float af0 = __shfl(aggs, qb + 0);
    float af1 = __shfl(aggs, qb + 1);
    float af2 = __shfl(aggs, qb + 2);
    float af3 = __shfl(aggs, qb + 3);

    int o0 = 8 * s;
    float h[8];
#pragma unroll
    for (int u = 0; u < 8; ++u) {
        int o = o0 + u;
        float a = af0 * sw1[0 * 33 + o] + af1 * sw1[1 * 33 + o]
                + af2 * sw1[2 * 33 + o] + af3 * sw1[3 * 33 + o];
        h[u] = fmaxf(a + sb1[o], 0.f);
    }

    float hf[32];
#pragma unroll
    for (int w = 0; w < 4; ++w)
#pragma unroll
        for (int u = 0; u < 8; ++u)
            hf[8 * w + u] = __shfl(h[u], qb + w);

    float* oc = xcat + (size_t)i * 68;
    if (s == 0) {
        oc[0] = xb[(size_t)n * FTOT];
        oc[1] = xb[(size_t)n * FTOT + 1];
    }
#pragma unroll
    for (int u = 0; u < 8; ++u) {
        int o = o0 + u;
        float a = 0.f;
#pragma unroll
        for (int k = 0; k < 32; ++k) a += hf[k] * sw2[k * 33 + o];
        oc[2 + o] = a + sb2[o];
    }
}

// ---------------- FUSED g2 + mlp: identical to round 16 (passed) ----------------
__global__ __launch_bounds__(256) void k_g2m(const float* __restrict__ xcat,
                                             const int* __restrict__ idx,
                                             const float* __restrict__ gw1, const float* __restrict__ gb1,
                                             const float* __restrict__ gw2, const float* __restrict__ gb2,
                                             const float* __restrict__ w1, const float* __restrict__ b1,
                                             const float* __restrict__ w2, const float* __restrict__ b2,
                                             const float* __restrict__ w3, const float* __restrict__ b3,
                                             const float* __restrict__ g,  const float* __restrict__ be,
                                             const float* __restrict__ mn, const float* __restrict__ vr,
                                             const float* __restrict__ ow, const float* __restrict__ ob,
                                             float* __restrict__ out) {
    __shared__ float sw1[32 * 33], sw2[32 * 33], sb1[32], sb2[32];
    __shared__ float xT[68][36];
    __shared__ float h1T[128][36];
    __shared__ float h2T[64][36];
    int t = threadIdx.x;
    int base = blockIdx.x * 32;

    for (int u = t; u < 1024; u += 256) {
        sw1[(u >> 5) * 33 + (u & 31)] = gw1[u];
        sw2[(u >> 5) * 33 + (u & 31)] = gw2[u];
    }
    if (t < 32) { sb1[t] = gb1[t]; sb2[t] = gb2[t]; }
    for (int u = t; u < 32 * 34; u += 256) {
        int p = u / 34, k = u - p * 34;
        xT[k][p] = xcat[(size_t)(base + p) * 68 + k];
    }
    __syncthreads();

    if (t < 128) {
        int pt = t >> 2;
        int s  = t & 3;
        int qb = (t & 63) & ~3;
        int i  = base + pt;
        int b  = i >> 12;

        float agg[8];
#pragma unroll
        for (int u = 0; u < 8; ++u) agg[u] = 0.f;
#pragma unroll
        for (int k = 0; k < KNN; ++k) {
            int nb = idx[(size_t)i * KNN + k];
            const float2* f2 = (const float2*)(xcat + ((size_t)b * NPTS + nb) * 68 + 2 + 8 * s);
#pragma unroll
            for (int w = 0; w < 4; ++w) {
                float2 a = f2[w];
                agg[2 * w]     += a.x;
                agg[2 * w + 1] += a.y;
            }
        }
#pragma unroll
        for (int u = 0; u < 8; ++u) agg[u] *= 0.125f;

        float af[32];
#pragma unroll
        for (int w = 0; w < 4; ++w)
#pragma unroll
            for (int u = 0; u < 8; ++u)
                af[8 * w + u] = __shfl(agg[u], qb + w);

        int o0 = 8 * s;
        float h[8];
#pragma unroll
        for (int u = 0; u < 8; ++u) {
            int o = o0 + u;
            float a = 0.f;
#pragma unroll
            for (int k = 0; k < 32; ++k) a += af[k] * sw1[k * 33 + o];
            h[u] = fmaxf(a + sb1[o], 0.f);
        }

        float hf[32];
#pragma unroll
        for (int w = 0; w < 4; ++w)
#pragma unroll
            for (int u = 0; u < 8; ++u)
                hf[8 * w + u] = __shfl(h[u], qb + w);

        if (s == 0) {
            xT[34][pt] = xT[0][pt];
            xT[35][pt] = xT[1][pt];
        }
#pragma unroll
        for (int u = 0; u < 8; ++u) {
            int o = o0 + u;
            float a = 0.f;
#pragma unroll
            for (int k = 0; k < 32; ++k) a += hf[k] * sw2[k * 33 + o];
            xT[36 + o][pt] = a + sb2[o];
        }
    }
    __syncthreads();

    int pq = t & 7;
    int oq = t >> 3;

    {
        float4 bb = *(const float4*)(b1 + 4 * oq);
        float4 a0 = make_float4(bb.x, bb.x, bb.x, bb.x);
        float4 a1 = make_float4(bb.y, bb.y, bb.y, bb.y);
        float4 a2 = make_float4(bb.z, bb.z, bb.z, bb.z);
        float4 a3 = make_float4(bb.w, bb.w, bb.w, bb.w);
#pragma unroll 4
        for (int k = 0; k < 68; ++k) {
            float4 xv = *(const float4*)&xT[k][4 * pq];
            float4 wv = *(const float4*)(w1 + (size_t)k * 128 + 4 * oq);
            a0.x += wv.x * xv.x; a0.y += wv.x * xv.y; a0.z += wv.x * xv.z; a0.w += wv.x * xv.w;
            a1.x += wv.y * xv.x; a1.y += wv.y * xv.y; a1.z += wv.y * xv.z; a1.w += wv.y * xv.w;
            a2.x += wv.z * xv.x; a2.y += wv.z * xv.y; a2.z += wv.z * xv.z; a2.w += wv.z * xv.w;
            a3.x += wv.w * xv.x; a3.y += wv.w * xv.y; a3.z += wv.w * xv.z; a3.w += wv.w * xv.w;
        }
        a0.x = fmaxf(a0.x, 0.f); a0.y = fmaxf(a0.y, 0.f); a0.z = fmaxf(a0.z, 0.f); a0.w = fmaxf(a0.w, 0.f);
        a1.x = fmaxf(a1.x, 0.f); a1.y = fmaxf(a1.y, 0.f); a1.z = fmaxf(a1.z, 0.f); a1.w = fmaxf(a1.w, 0.f);
        a2.x = fmaxf(a2.x, 0.f); a2.y = fmaxf(a2.y, 0.f); a2.z = fmaxf(a2.z, 0.f); a2.w = fmaxf(a2.w, 0.f);
        a3.x = fmaxf(a3.x, 0.f); a3.y = fmaxf(a3.y, 0.f); a3.z = fmaxf(a3.z, 0.f); a3.w = fmaxf(a3.w, 0.f);
        *(float4*)&h1T[4 * oq + 0][4 * pq] = a0;
        *(float4*)&h1T[4 * oq + 1][4 * pq] = a1;
        *(float4*)&h1T[4 * oq + 2][4 * pq] = a2;
        *(float4*)&h1T[4 * oq + 3][4 * pq] = a3;
    }
    __syncthreads();

    if (t < 128) {
        float4 bb = *(const float4*)(b2 + 4 * oq);
        float4 a0 = make_float4(bb.x, bb.x, bb.x, bb.x);
        float4 a1 = make_float4(bb.y, bb.y, bb.y, bb.y);
        float4 a2 = make_float4(bb.z, bb.z, bb.z, bb.z);
        float4 a3 = make_float4(bb.w, bb.w, bb.w, bb.w);
#pragma unroll 4
        for (int k = 0; k < 128; ++k) {
            float4 xv = *(const float4*)&h1T[k][4 * pq];
            float4 wv = *(const float4*)(w2 + (size_t)k * 64 + 4 * oq);
            a0.x += wv.x * xv.x; a0.y += wv.x * xv.y; a0.z += wv.x * xv.z; a0.w += wv.x * xv.w;
            a1.x += wv.y * xv.x; a1.y += wv.y * xv.y; a1.z += wv.y * xv.z; a1.w += wv.y * xv.w;
            a2.x += wv.z * xv.x; a2.y += wv.z * xv.y; a2.z += wv.z * xv.z; a2.w += wv.z * xv.w;
            a3.x += wv.w * xv.x; a3.y += wv.w * xv.y; a3.z += wv.w * xv.z; a3.w += wv.w * xv.w;
        }
        a0.x = fmaxf(a0.x, 0.f); a0.y = fmaxf(a0.y, 0.f); a0.z = fmaxf(a0.z, 0.f); a0.w = fmaxf(a0.w, 0.f);
        a1.x = fmaxf(a1.x, 0.f); a1.y = fmaxf(a1.y, 0.f); a1.z = fmaxf(a1.z, 0.f); a1.w = fmaxf(a1.w, 0.f);
        a2.x = fmaxf(a2.x, 0.f); a2.y = fmaxf(a2.y, 0.f); a2.z = fmaxf(a2.z, 0.f); a2.w = fmaxf(a2.w, 0.f);
        a3.x = fmaxf(a3.x, 0.f); a3.y = fmaxf(a3.y, 0.f); a3.z = fmaxf(a3.z, 0.f); a3.w = fmaxf(a3.w, 0.f);
        *(float4*)&h2T[4 * oq + 0][4 * pq] = a0;
        *(float4*)&h2T[4 * oq + 1][4 * pq] = a1;
        *(float4*)&h2T[4 * oq + 2][4 * pq] = a2;
        *(float4*)&h2T[4 * oq + 3][4 * pq] = a3;
    }
    __syncthreads();

    if (t < 64) {
        float4 bb = *(const float4*)(b3 + 4 * oq);
        float4 a0 = make_float4(bb.x, bb.x, bb.x, bb.x);
        float4 a1 = make_float4(bb.y, bb.y, bb.y, bb.y);
        float4 a2 = make_float4(bb.z, bb.z, bb.z, bb.z);
        float4 a3 = make_float4(bb.w, bb.w, bb.w, bb.w);
#pragma unroll 4
        for (int k = 0; k < 64; ++k) {
            float4 xv = *(const float4*)&h2T[k][4 * pq];
            float4 wv = *(const float4*)(w3 + (size_t)k * 32 + 4 * oq);
            a0.x += wv.x * xv.x; a0.y += wv.x * xv.y; a0.z += wv.x * xv.z; a0.w += wv.x * xv.w;
            a1.x += wv.y * xv.x; a1.y += wv.y * xv.y; a1.z += wv.y * xv.z; a1.w += wv.y * xv.w;
            a2.x += wv.z * xv.x; a2.y += wv.z * xv.y; a2.z += wv.z * xv.z; a2.w += wv.z * xv.w;
            a3.x += wv.w * xv.x; a3.y += wv.w * xv.y; a3.z += wv.w * xv.z; a3.w += wv.w * xv.w;
        }
        a0.x = fmaxf(a0.x, 0.f); a0.y = fmaxf(a0.y, 0.f); a0.z = fmaxf(a0.z, 0.f); a0.w = fmaxf(a0.w, 0.f);
        a1.x = fmaxf(a1.x, 0.f); a1.y = fmaxf(a1.y, 0.f); a1.z = fmaxf(a1.z, 0.f); a1.w = fmaxf(a1.w, 0.f);
        a2.x = fmaxf(a2.x, 0.f); a2.y = fmaxf(a2.y, 0.f); a2.z = fmaxf(a2.z, 0.f); a2.w = fmaxf(a2.w, 0.f);
        a3.x = fmaxf(a3.x, 0.f); a3.y = fmaxf(a3.y, 0.f); a3.z = fmaxf(a3.z, 0.f); a3.w = fmaxf(a3.w, 0.f);
        int c0 = 4 * oq;
        float s0 = g[c0 + 0] * rsqrtf(vr[c0 + 0] + EPSV);
        float s1 = g[c0 + 1] * rsqrtf(vr[c0 + 1] + EPSV);
        float s2 = g[c0 + 2] * rsqrtf(vr[c0 + 2] + EPSV);
        float s3 = g[c0 + 3] * rsqrtf(vr[c0 + 3] + EPSV);
        float w0 = s0 * ow[c0 + 0], w1c = s1 * ow[c0 + 1];
        float w2c = s2 * ow[c0 + 2], w3c = s3 * ow[c0 + 3];
        float tt = (be[c0 + 0] - mn[c0 + 0] * s0) * ow[c0 + 0]
                 + (be[c0 + 1] - mn[c0 + 1] * s1) * ow[c0 + 1]
                 + (be[c0 + 2] - mn[c0 + 2] * s2) * ow[c0 + 2]
                 + (be[c0 + 3] - mn[c0 + 3] * s3) * ow[c0 + 3];
        float4 s;
        s.x = a0.x * w0 + a1.x * w1c + a2.x * w2c + a3.x * w3c;
        s.y = a0.y * w0 + a1.y * w1c + a2.y * w2c + a3.y * w3c;
        s.z = a0.z * w0 + a1.z * w1c + a2.z * w2c + a3.z * w3c;
        s.w = a0.w * w0 + a1.w * w1c + a2.w * w2c + a3.w * w3c;
#pragma unroll
        for (int msk = 8; msk <= 32; msk <<= 1) {
            s.x += __shfl_xor(s.x, msk);
            s.y += __shfl_xor(s.y, msk);
            s.z += __shfl_xor(s.z, msk);
            s.w += __shfl_xor(s.w, msk);
            tt  += __shfl_xor(tt,  msk);
        }
        if (oq == 0) {
            float c = tt + ob[0];
            *(float4*)(out + base + 4 * pq) = make_float4(s.x + c, s.y + c, s.z + c, s.w + c);
        }
    }
}

extern "C" void kernel_launch(void* const* d_in, const int* in_sizes, int n_in,
                              void* d_out, int out_size, void* d_ws, size_t ws_size,
                              hipStream_t stream) {
    const float* inputs    = (const float*)d_in[0];
    const float* bn1_gamma = (const float*)d_in[1];
    const float* bn1_beta  = (const float*)d_in[2];
    const float* bn1_mean  = (const float*)d_in[3];
    const float* bn1_var   = (const float*)d_in[4];
    const float* g1_w1 = (const float*)d_in[5];
    const float* g1_b1 = (const float*)d_in[6];
    const float* g1_w2 = (const float*)d_in[7];
    const float* g1_b2 = (const float*)d_in[8];
    const float* g2_w1 = (const float*)d_in[9];
    const float* g2_b1 = (const float*)d_in[10];
    const float* g2_w2 = (const float*)d_in[11];
    const float* g2_b2 = (const float*)d_in[12];
    const float* d1_w = (const float*)d_in[13];
    const float* d1_b = (const float*)d_in[14];
    const float* d2_w = (const float*)d_in[15];
    const float* d2_b = (const float*)d_in[16];
    const float* d3_w = (const float*)d_in[17];
    const float* d3_b = (const float*)d_in[18];
    const float* bn2_gamma = (const float*)d_in[19];
    const float* bn2_beta  = (const float*)d_in[20];
    const float* bn2_mean  = (const float*)d_in[21];
    const float* bn2_var   = (const float*)d_in[22];
    const float* out_w = (const float*)d_in[23];
    const float* out_b = (const float*)d_in[24];
    float* out = (float*)d_out;

    const size_t BN = (size_t)BTOT * NPTS;
    char* ws = (char*)d_ws;
    size_t off = 0;
    auto alloc = [&](size_t bytes) { char* p = ws + off; off += (bytes + 255) & ~(size_t)255; return p; };
    float*  x    = (float*) alloc(BN * FTOT * sizeof(float));
    float2* pos  = (float2*)alloc(BN * sizeof(float2));
    int*    idx  = (int*)   alloc(BN * KNN  * sizeof(int));
    float*  xcat = (float*) alloc(BN * 68   * sizeof(float));   // only cols [0,34) live in global
    (void)ws_size; (void)n_in; (void)in_sizes; (void)out_size;

    k_bn1<<<dim3(64),   dim3(256), 0, stream>>>(inputs, bn1_gamma, bn1_beta, bn1_mean, bn1_var, x, pos);
    k_knn<<<dim3(2048), dim3(512), 0, stream>>>(pos, idx);
    k_g1 <<<dim3(256),  dim3(256), 0, stream>>>(x, idx, g1_w1, g1_b1, g1_w2, g1_b2, xcat);
    k_g2m<<<dim3(512),  dim3(256), 0, stream>>>(xcat, idx,
                                                g2_w1, g2_b1, g2_w2, g2_b2,
                                                d1_w, d1_b, d2_w, d2_b, d3_w, d3_b,
                                                bn2_gamma, bn2_beta, bn2_mean, bn2_var,
                                                out_w, out_b, out);
}

// Round 18
// 97.331 us; speedup vs baseline: 1.0205x; 1.0205x over previous
//
#include <hip/hip_runtime.h>
#include <hip/hip_bf16.h>

#define BTOT 4
#define NPTS 4096
#define FTOT 6
#define KNN 8
#define EPSV 1e-3f

// xor-butterfly on u64 via ds_swizzle BitMode (1 LDS-op per 32-bit word).
template <int P>
__device__ __forceinline__ unsigned long long swz_xor_u64(unsigned long long v) {
    unsigned lo = (unsigned)v, hi = (unsigned)(v >> 32);
    lo = (unsigned)__builtin_amdgcn_ds_swizzle((int)lo, P);
    hi = (unsigned)__builtin_amdgcn_ds_swizzle((int)hi, P);
    return ((unsigned long long)hi << 32) | lo;
}
#define MERGE_STEP(P) { unsigned long long o_ = swz_xor_u64<P>(mn); mn = (o_ < mn) ? o_ : mn; }
#define MERGE_MIN_U64_32() \
    MERGE_STEP(0x041F) MERGE_STEP(0x081F) MERGE_STEP(0x101F) MERGE_STEP(0x201F) MERGE_STEP(0x401F)

// ---------------- bn1 ----------------
__global__ __launch_bounds__(256) void k_bn1(const float* __restrict__ in,
                                             const float* __restrict__ g,
                                             const float* __restrict__ b,
                                             const float* __restrict__ m,
                                             const float* __restrict__ v,
                                             float* __restrict__ x,
                                             float2* __restrict__ pos) {
    int i = blockIdx.x * 256 + threadIdx.x;
    if (i >= BTOT * NPTS) return;
    float o[FTOT];
#pragma unroll
    for (int f = 0; f < FTOT; ++f) {
        float val = in[(size_t)i * FTOT + f];
        o[f] = (val - m[f]) * rsqrtf(v[f] + EPSV) * g[f] + b[f];
        x[(size_t)i * FTOT + f] = o[f];
    }
    pos[i] = make_float2(o[0], o[1]);
}

// ---------------- KNN v6s: 32 lanes/query (measured optimum: 16->74us, 32->60us, 64->65us).
// SELECTION MATH FROZEN: u64 keys, single-level insert, sentinel init, 9-round extraction. ----------------
__global__ __launch_bounds__(512) void k_knn(const float2* __restrict__ posg,
                                             int* __restrict__ idx) {
    __shared__ float2 spos[NPTS];  // 32 KB
    int b  = blockIdx.x >> 8;                 // 256 blocks per batch
    int q0 = (blockIdx.x & 255) << 4;         // 16 queries per block
    int t  = threadIdx.x;
    const float2* pb = posg + (size_t)b * NPTS;
    for (int j = t; j < NPTS; j += 512) spos[j] = pb[j];
    __syncthreads();

    int lq = t >> 5;          // local query 0..15
    int p  = t & 31;          // partition lane 0..31
    int qq = q0 + lq;
    float2 q = spos[qq];

    // ---- pass 1: per-lane lexicographic-min u64 key, 4 independent accumulators ----
    unsigned long long bm0 = ~0ULL, bm1 = ~0ULL, bm2 = ~0ULL, bm3 = ~0ULL;
    for (int jj = 0; jj < NPTS / 32; jj += 4) {
        int j0 = ((jj + 0) << 5) + p;
        int j1 = ((jj + 1) << 5) + p;
        int j2 = ((jj + 2) << 5) + p;
        int j3 = ((jj + 3) << 5) + p;
        float2 p0 = spos[j0], p1 = spos[j1], p2 = spos[j2], p3 = spos[j3];
        float d0 = __fadd_rn(__fmul_rn(q.x - p0.x, q.x - p0.x), __fmul_rn(q.y - p0.y, q.y - p0.y));
        float d1 = __fadd_rn(__fmul_rn(q.x - p1.x, q.x - p1.x), __fmul_rn(q.y - p1.y, q.y - p1.y));
        float d2 = __fadd_rn(__fmul_rn(q.x - p2.x, q.x - p2.x), __fmul_rn(q.y - p2.y, q.y - p2.y));
        float d3 = __fadd_rn(__fmul_rn(q.x - p3.x, q.x - p3.x), __fmul_rn(q.y - p3.y, q.y - p3.y));
        unsigned long long k0 = ((unsigned long long)__float_as_uint(d0) << 32) | (unsigned)j0;
        unsigned long long k1 = ((unsigned long long)__float_as_uint(d1) << 32) | (unsigned)j1;
        unsigned long long k2 = ((unsigned long long)__float_as_uint(d2) << 32) | (unsigned)j2;
        unsigned long long k3 = ((unsigned long long)__float_as_uint(d3) << 32) | (unsigned)j3;
        bm0 = k0 < bm0 ? k0 : bm0;
        bm1 = k1 < bm1 ? k1 : bm1;
        bm2 = k2 < bm2 ? k2 : bm2;
        bm3 = k3 < bm3 ? k3 : bm3;
    }
    unsigned long long bma = bm0 < bm1 ? bm0 : bm1;
    unsigned long long bmb = bm2 < bm3 ? bm2 : bm3;
    unsigned long long bm  = bma < bmb ? bma : bmb;

    // ---- threshold r = 9th smallest of the 32 lane-min keys ----
    unsigned long long KK = bm, r = 0;
#pragma unroll
    for (int rd = 0; rd < 9; ++rd) {
        unsigned long long mn = KK;
        MERGE_MIN_U64_32()
        if (KK == mn) KK = ~0ULL;   // owner retires (keys unique)
        r = mn;
    }
    unsigned long long sent = r + 1;  // keys unique: key <= r  <=>  key < sent

    // ---- pass 2: per-lane top-9 insertion, single-level if (required structure) ----
    unsigned long long K[9];
#pragma unroll
    for (int m = 0; m < 9; ++m) K[m] = sent;

#pragma unroll 4
    for (int jj = 0; jj < NPTS / 32; ++jj) {
        int j = (jj << 5) + p;
        float2 pt = spos[j];
        float dx = q.x - pt.x;
        float dy = q.y - pt.y;
        float d2 = __fadd_rn(__fmul_rn(dx, dx), __fmul_rn(dy, dy));  // no FMA contraction
        unsigned long long key = ((unsigned long long)__float_as_uint(d2) << 32) | (unsigned)j;
        if (key < K[8]) {
            K[8] = key;
#pragma unroll
            for (int m = 8; m > 0; --m) {
                bool sw = K[m] < K[m - 1];
                unsigned long long a = sw ? K[m - 1] : K[m];
                unsigned long long c = sw ? K[m] : K[m - 1];
                K[m] = a; K[m - 1] = c;
            }
        }
    }

    // ---- 9 extraction rounds: global min over the 32-lane group (>=9 real keys < sent) ----
    int rec = qq;   // inert when correct; keeps downstream in-range if not
#pragma unroll
    for (int rd = 0; rd < 9; ++rd) {
        unsigned long long mn = K[0];
        MERGE_MIN_U64_32()
        if (K[0] == mn) {   // this lane owned the min: advance its sorted list
#pragma unroll
            for (int i = 0; i < 8; ++i) K[i] = K[i + 1];
            K[8] = ~0ULL;
        }
        if (rd >= 1 && p == rd - 1) rec = (int)(unsigned)mn;   // rounds 1..8 = the 8 neighbors
    }
    rec &= (NPTS - 1);   // hard-mask to [0,4096): downstream gathers can never fault
    if (p < 8)
        idx[((size_t)b * NPTS + qq) * KNN + p] = rec;
}

// ---------------- gravnet1 v2: 4 lanes/point ----------------
__global__ __launch_bounds__(256) void k_g1(const float* __restrict__ x,
                                            const int* __restrict__ idx,
                                            const float* __restrict__ w1,
                                            const float* __restrict__ b1,
                                            const float* __restrict__ w2,
                                            const float* __restrict__ b2,
                                            float* __restrict__ xcat) {
    __shared__ float sw1[4 * 33], sw2[32 * 33], sb1[32], sb2[32];
    int t = threadIdx.x;
    if (t < 128) sw1[(t >> 5) * 33 + (t & 31)] = w1[t];
    for (int u = t; u < 1024; u += 256) sw2[(u >> 5) * 33 + (u & 31)] = w2[u];
    if (t < 32) { sb1[t] = b1[t]; sb2[t] = b2[t]; }
    __syncthreads();

    int i = blockIdx.x * 64 + (t >> 2);   // point
    int s = t & 3;                        // sublane
    int qb = (t & 63) & ~3;               // quad base lane within wave
    int b = i >> 12;
    int n = i & (NPTS - 1);
    const float* xb = x + (size_t)b * NPTS * FTOT;

    float aggs = 0.f;
#pragma unroll
    for (int k = 0; k < KNN; ++k) {
        int nb = idx[(size_t)i * KNN + k];
        aggs += xb[(size_t)nb * FTOT + 2 + s];
    }
    aggs *= 0.125f;

    float af0 = __shfl(aggs, qb + 0);
    float af1 = __shfl(aggs, qb + 1);
    float af2 = __shfl(aggs, qb + 2);
    float af3 = __shfl(aggs, qb + 3);

    int o0 = 8 * s;
    float h[8];
#pragma unroll
    for (int u = 0; u < 8; ++u) {
        int o = o0 + u;
        float a = af0 * sw1[0 * 33 + o] + af1 * sw1[1 * 33 + o]
                + af2 * sw1[2 * 33 + o] + af3 * sw1[3 * 33 + o];
        h[u] = fmaxf(a + sb1[o], 0.f);
    }

    float hf[32];
#pragma unroll
    for (int w = 0; w < 4; ++w)
#pragma unroll
        for (int u = 0; u < 8; ++u)
            hf[8 * w + u] = __shfl(h[u], qb + w);

    float* oc = xcat + (size_t)i * 68;
    if (s == 0) {
        oc[0] = xb[(size_t)n * FTOT];
        oc[1] = xb[(size_t)n * FTOT + 1];
    }
#pragma unroll
    for (int u = 0; u < 8; ++u) {
        int o = o0 + u;
        float a = 0.f;
#pragma unroll
        for (int k = 0; k < 32; ++k) a += hf[k] * sw2[k * 33 + o];
        oc[2 + o] = a + sb2[o];
    }
}

// ---------------- FUSED g2 + mlp ----------------
__global__ __launch_bounds__(256) void k_g2m(const float* __restrict__ xcat,
                                             const int* __restrict__ idx,
                                             const float* __restrict__ gw1, const float* __restrict__ gb1,
                                             const float* __restrict__ gw2, const float* __restrict__ gb2,
                                             const float* __restrict__ w1, const float* __restrict__ b1,
                                             const float* __restrict__ w2, const float* __restrict__ b2,
                                             const float* __restrict__ w3, const float* __restrict__ b3,
                                             const float* __restrict__ g,  const float* __restrict__ be,
                                             const float* __restrict__ mn, const float* __restrict__ vr,
                                             const float* __restrict__ ow, const float* __restrict__ ob,
                                             float* __restrict__ out) {
    __shared__ float sw1[32 * 33], sw2[32 * 33], sb1[32], sb2[32];
    __shared__ float xT[68][36];
    __shared__ float h1T[128][36];
    __shared__ float h2T[64][36];
    int t = threadIdx.x;
    int base = blockIdx.x * 32;

    for (int u = t; u < 1024; u += 256) {
        sw1[(u >> 5) * 33 + (u & 31)] = gw1[u];
        sw2[(u >> 5) * 33 + (u & 31)] = gw2[u];
    }
    if (t < 32) { sb1[t] = gb1[t]; sb2[t] = gb2[t]; }
    for (int u = t; u < 32 * 34; u += 256) {
        int p = u / 34, k = u - p * 34;
        xT[k][p] = xcat[(size_t)(base + p) * 68 + k];
    }
    __syncthreads();

    if (t < 128) {
        int pt = t >> 2;
        int s  = t & 3;
        int qb = (t & 63) & ~3;
        int i  = base + pt;
        int b  = i >> 12;

        float agg[8];
#pragma unroll
        for (int u = 0; u < 8; ++u) agg[u] = 0.f;
#pragma unroll
        for (int k = 0; k < KNN; ++k) {
            int nb = idx[(size_t)i * KNN + k];
            const float2* f2 = (const float2*)(xcat + ((size_t)b * NPTS + nb) * 68 + 2 + 8 * s);
#pragma unroll
            for (int w = 0; w < 4; ++w) {
                float2 a = f2[w];
                agg[2 * w]     += a.x;
                agg[2 * w + 1] += a.y;
            }
        }
#pragma unroll
        for (int u = 0; u < 8; ++u) agg[u] *= 0.125f;

        float af[32];
#pragma unroll
        for (int w = 0; w < 4; ++w)
#pragma unroll
            for (int u = 0; u < 8; ++u)
                af[8 * w + u] = __shfl(agg[u], qb + w);

        int o0 = 8 * s;
        float h[8];
#pragma unroll
        for (int u = 0; u < 8; ++u) {
            int o = o0 + u;
            float a = 0.f;
#pragma unroll
            for (int k = 0; k < 32; ++k) a += af[k] * sw1[k * 33 + o];
            h[u] = fmaxf(a + sb1[o], 0.f);
        }

        float hf[32];
#pragma unroll
        for (int w = 0; w < 4; ++w)
#pragma unroll
            for (int u = 0; u < 8; ++u)
                hf[8 * w + u] = __shfl(h[u], qb + w);

        if (s == 0) {
            xT[34][pt] = xT[0][pt];
            xT[35][pt] = xT[1][pt];
        }
#pragma unroll
        for (int u = 0; u < 8; ++u) {
            int o = o0 + u;
            float a = 0.f;
#pragma unroll
            for (int k = 0; k < 32; ++k) a += hf[k] * sw2[k * 33 + o];
            xT[36 + o][pt] = a + sb2[o];
        }
    }
    __syncthreads();

    int pq = t & 7;
    int oq = t >> 3;

    {
        float4 bb = *(const float4*)(b1 + 4 * oq);
        float4 a0 = make_float4(bb.x, bb.x, bb.x, bb.x);
        float4 a1 = make_float4(bb.y, bb.y, bb.y, bb.y);
        float4 a2 = make_float4(bb.z, bb.z, bb.z, bb.z);
        float4 a3 = make_float4(bb.w, bb.w, bb.w, bb.w);
#pragma unroll 4
        for (int k = 0; k < 68; ++k) {
            float4 xv = *(const float4*)&xT[k][4 * pq];
            float4 wv = *(const float4*)(w1 + (size_t)k * 128 + 4 * oq);
            a0.x += wv.x * xv.x; a0.y += wv.x * xv.y; a0.z += wv.x * xv.z; a0.w += wv.x * xv.w;
            a1.x += wv.y * xv.x; a1.y += wv.y * xv.y; a1.z += wv.y * xv.z; a1.w += wv.y * xv.w;
            a2.x += wv.z * xv.x; a2.y += wv.z * xv.y; a2.z += wv.z * xv.z; a2.w += wv.z * xv.w;
            a3.x += wv.w * xv.x; a3.y += wv.w * xv.y; a3.z += wv.w * xv.z; a3.w += wv.w * xv.w;
        }
        a0.x = fmaxf(a0.x, 0.f); a0.y = fmaxf(a0.y, 0.f); a0.z = fmaxf(a0.z, 0.f); a0.w = fmaxf(a0.w, 0.f);
        a1.x = fmaxf(a1.x, 0.f); a1.y = fmaxf(a1.y, 0.f); a1.z = fmaxf(a1.z, 0.f); a1.w = fmaxf(a1.w, 0.f);
        a2.x = fmaxf(a2.x, 0.f); a2.y = fmaxf(a2.y, 0.f); a2.z = fmaxf(a2.z, 0.f); a2.w = fmaxf(a2.w, 0.f);
        a3.x = fmaxf(a3.x, 0.f); a3.y = fmaxf(a3.y, 0.f); a3.z = fmaxf(a3.z, 0.f); a3.w = fmaxf(a3.w, 0.f);
        *(float4*)&h1T[4 * oq + 0][4 * pq] = a0;
        *(float4*)&h1T[4 * oq + 1][4 * pq] = a1;
        *(float4*)&h1T[4 * oq + 2][4 * pq] = a2;
        *(float4*)&h1T[4 * oq + 3][4 * pq] = a3;
    }
    __syncthreads();

    if (t < 128) {
        float4 bb = *(const float4*)(b2 + 4 * oq);
        float4 a0 = make_float4(bb.x, bb.x, bb.x, bb.x);
        float4 a1 = make_float4(bb.y, bb.y, bb.y, bb.y);
        float4 a2 = make_float4(bb.z, bb.z, bb.z, bb.z);
        float4 a3 = make_float4(bb.w, bb.w, bb.w, bb.w);
#pragma unroll 4
        for (int k = 0; k < 128; ++k) {
            float4 xv = *(const float4*)&h1T[k][4 * pq];
            float4 wv = *(const float4*)(w2 + (size_t)k * 64 + 4 * oq);
            a0.x += wv.x * xv.x; a0.y += wv.x * xv.y; a0.z += wv.x * xv.z; a0.w += wv.x * xv.w;
            a1.x += wv.y * xv.x; a1.y += wv.y * xv.y; a1.z += wv.y * xv.z; a1.w += wv.y * xv.w;
            a2.x += wv.z * xv.x; a2.y += wv.z * xv.y; a2.z += wv.z * xv.z; a2.w += wv.z * xv.w;
            a3.x += wv.w * xv.x; a3.y += wv.w * xv.y; a3.z += wv.w * xv.z; a3.w += wv.w * xv.w;
        }
        a0.x = fmaxf(a0.x, 0.f); a0.y = fmaxf(a0.y, 0.f); a0.z = fmaxf(a0.z, 0.f); a0.w = fmaxf(a0.w, 0.f);
        a1.x = fmaxf(a1.x, 0.f); a1.y = fmaxf(a1.y, 0.f); a1.z = fmaxf(a1.z, 0.f); a1.w = fmaxf(a1.w, 0.f);
        a2.x = fmaxf(a2.x, 0.f); a2.y = fmaxf(a2.y, 0.f); a2.z = fmaxf(a2.z, 0.f); a2.w = fmaxf(a2.w, 0.f);
        a3.x = fmaxf(a3.x, 0.f); a3.y = fmaxf(a3.y, 0.f); a3.z = fmaxf(a3.z, 0.f); a3.w = fmaxf(a3.w, 0.f);
        *(float4*)&h2T[4 * oq + 0][4 * pq] = a0;
        *(float4*)&h2T[4 * oq + 1][4 * pq] = a1;
        *(float4*)&h2T[4 * oq + 2][4 * pq] = a2;
        *(float4*)&h2T[4 * oq + 3][4 * pq] = a3;
    }
    __syncthreads();

    if (t < 64) {
        float4 bb = *(const float4*)(b3 + 4 * oq);
        float4 a0 = make_float4(bb.x, bb.x, bb.x, bb.x);
        float4 a1 = make_float4(bb.y, bb.y, bb.y, bb.y);
        float4 a2 = make_float4(bb.z, bb.z, bb.z, bb.z);
        float4 a3 = make_float4(bb.w, bb.w, bb.w, bb.w);
#pragma unroll 4
        for (int k = 0; k < 64; ++k) {
            float4 xv = *(const float4*)&h2T[k][4 * pq];
            float4 wv = *(const float4*)(w3 + (size_t)k * 32 + 4 * oq);
            a0.x += wv.x * xv.x; a0.y += wv.x * xv.y; a0.z += wv.x * xv.z; a0.w += wv.x * xv.w;
            a1.x += wv.y * xv.x; a1.y += wv.y * xv.y; a1.z += wv.y * xv.z; a1.w += wv.y * xv.w;
            a2.x += wv.z * xv.x; a2.y += wv.z * xv.y; a2.z += wv.z * xv.z; a2.w += wv.z * xv.w;
            a3.x += wv.w * xv.x; a3.y += wv.w * xv.y; a3.z += wv.w * xv.z; a3.w += wv.w * xv.w;
        }
        a0.x = fmaxf(a0.x, 0.f); a0.y = fmaxf(a0.y, 0.f); a0.z = fmaxf(a0.z, 0.f); a0.w = fmaxf(a0.w, 0.f);
        a1.x = fmaxf(a1.x, 0.f); a1.y = fmaxf(a1.y, 0.f); a1.z = fmaxf(a1.z, 0.f); a1.w = fmaxf(a1.w, 0.f);
        a2.x = fmaxf(a2.x, 0.f); a2.y = fmaxf(a2.y, 0.f); a2.z = fmaxf(a2.z, 0.f); a2.w = fmaxf(a2.w, 0.f);
        a3.x = fmaxf(a3.x, 0.f); a3.y = fmaxf(a3.y, 0.f); a3.z = fmaxf(a3.z, 0.f); a3.w = fmaxf(a3.w, 0.f);
        int c0 = 4 * oq;
        float s0 = g[c0 + 0] * rsqrtf(vr[c0 + 0] + EPSV);
        float s1 = g[c0 + 1] * rsqrtf(vr[c0 + 1] + EPSV);
        float s2 = g[c0 + 2] * rsqrtf(vr[c0 + 2] + EPSV);
        float s3 = g[c0 + 3] * rsqrtf(vr[c0 + 3] + EPSV);
        float w0 = s0 * ow[c0 + 0], w1c = s1 * ow[c0 + 1];
        float w2c = s2 * ow[c0 + 2], w3c = s3 * ow[c0 + 3];
        float tt = (be[c0 + 0] - mn[c0 + 0] * s0) * ow[c0 + 0]
                 + (be[c0 + 1] - mn[c0 + 1] * s1) * ow[c0 + 1]
                 + (be[c0 + 2] - mn[c0 + 2] * s2) * ow[c0 + 2]
                 + (be[c0 + 3] - mn[c0 + 3] * s3) * ow[c0 + 3];
        float4 s;
        s.x = a0.x * w0 + a1.x * w1c + a2.x * w2c + a3.x * w3c;
        s.y = a0.y * w0 + a1.y * w1c + a2.y * w2c + a3.y * w3c;
        s.z = a0.z * w0 + a1.z * w1c + a2.z * w2c + a3.z * w3c;
        s.w = a0.w * w0 + a1.w * w1c + a2.w * w2c + a3.w * w3c;
#pragma unroll
        for (int msk = 8; msk <= 32; msk <<= 1) {
            s.x += __shfl_xor(s.x, msk);
            s.y += __shfl_xor(s.y, msk);
            s.z += __shfl_xor(s.z, msk);
            s.w += __shfl_xor(s.w, msk);
            tt  += __shfl_xor(tt,  msk);
        }
        if (oq == 0) {
            float c = tt + ob[0];
            *(float4*)(out + base + 4 * pq) = make_float4(s.x + c, s.y + c, s.z + c, s.w + c);
        }
    }
}

extern "C" void kernel_launch(void* const* d_in, const int* in_sizes, int n_in,
                              void* d_out, int out_size, void* d_ws, size_t ws_size,
                              hipStream_t stream) {
    const float* inputs    = (const float*)d_in[0];
    const float* bn1_gamma = (const float*)d_in[1];
    const float* bn1_beta  = (const float*)d_in[2];
    const float* bn1_mean  = (const float*)d_in[3];
    const float* bn1_var   = (const float*)d_in[4];
    const float* g1_w1 = (const float*)d_in[5];
    const float* g1_b1 = (const float*)d_in[6];
    const float* g1_w2 = (const float*)d_in[7];
    const float* g1_b2 = (const float*)d_in[8];
    const float* g2_w1 = (const float*)d_in[9];
    const float* g2_b1 = (const float*)d_in[10];
    const float* g2_w2 = (const float*)d_in[11];
    const float* g2_b2 = (const float*)d_in[12];
    const float* d1_w = (const float*)d_in[13];
    const float* d1_b = (const float*)d_in[14];
    const float* d2_w = (const float*)d_in[15];
    const float* d2_b = (const float*)d_in[16];
    const float* d3_w = (const float*)d_in[17];
    const float* d3_b = (const float*)d_in[18];
    const float* bn2_gamma = (const float*)d_in[19];
    const float* bn2_beta  = (const float*)d_in[20];
    const float* bn2_mean  = (const float*)d_in[21];
    const float* bn2_var   = (const float*)d_in[22];
    const float* out_w = (const float*)d_in[23];
    const float* out_b = (const float*)d_in[24];
    float* out = (float*)d_out;

    const size_t BN = (size_t)BTOT * NPTS;
    char* ws = (char*)d_ws;
    size_t off = 0;
    auto alloc = [&](size_t bytes) { char* p = ws + off; off += (bytes + 255) & ~(size_t)255; return p; };
    float*  x    = (float*) alloc(BN * FTOT * sizeof(float));
    float2* pos  = (float2*)alloc(BN * sizeof(float2));
    int*    idx  = (int*)   alloc(BN * KNN  * sizeof(int));
    float*  xcat = (float*) alloc(BN * 68   * sizeof(float));   // only cols [0,34) live in global
    (void)ws_size; (void)n_in; (void)in_sizes; (void)out_size;

    k_bn1<<<dim3(64),   dim3(256), 0, stream>>>(inputs, bn1_gamma, bn1_beta, bn1_mean, bn1_var, x, pos);
    k_knn<<<dim3(1024), dim3(512), 0, stream>>>(pos, idx);
    k_g1 <<<dim3(256),  dim3(256), 0, stream>>>(x, idx, g1_w1, g1_b1, g1_w2, g1_b2, xcat);
    k_g2m<<<dim3(512),  dim3(256), 0, stream>>>(xcat, idx,
                                                g2_w1, g2_b1, g2_w2, g2_b2,
                                                d1_w, d1_b, d2_w, d2_b, d3_w, d3_b,
                                                bn2_gamma, bn2_beta, bn2_mean, bn2_var,
                                                out_w, out_b, out);
}

// Round 19
// 90.427 us; speedup vs baseline: 1.0984x; 1.0764x over previous
//
#include <hip/hip_runtime.h>
#include <hip/hip_bf16.h>

#define BTOT 4
#define NPTS 4096
#define FTOT 6
#define KNN 8
#define EPSV 1e-3f

// xor-butterfly on u64 via ds_swizzle BitMode (1 LDS-op per 32-bit word).
template <int P>
__device__ __forceinline__ unsigned long long swz_xor_u64(unsigned long long v) {
    unsigned lo = (unsigned)v, hi = (unsigned)(v >> 32);
    lo = (unsigned)__builtin_amdgcn_ds_swizzle((int)lo, P);
    hi = (unsigned)__builtin_amdgcn_ds_swizzle((int)hi, P);
    return ((unsigned long long)hi << 32) | lo;
}
#define MERGE_STEP(P) { unsigned long long o_ = swz_xor_u64<P>(mn); mn = (o_ < mn) ? o_ : mn; }
#define MERGE_MIN_U64_32() \
    MERGE_STEP(0x041F) MERGE_STEP(0x081F) MERGE_STEP(0x101F) MERGE_STEP(0x201F) MERGE_STEP(0x401F)

// ---------------- KNN v6s + inline bn1 on positions (identical formula, per-point same bits;
// bn1 is a monotone map on d2, so selection is unchanged). SELECTION MATH FROZEN. ----------------
__global__ __launch_bounds__(512) void k_knn(const float* __restrict__ in,
                                             const float* __restrict__ gbn,
                                             const float* __restrict__ bbn,
                                             const float* __restrict__ mbn,
                                             const float* __restrict__ vbn,
                                             int* __restrict__ idx) {
    __shared__ float2 spos[NPTS];  // 32 KB
    int b  = blockIdx.x >> 8;                 // 256 blocks per batch
    int q0 = (blockIdx.x & 255) << 4;         // 16 queries per block
    int t  = threadIdx.x;

    float ga0 = gbn[0], be0 = bbn[0], mu0 = mbn[0], rs0 = rsqrtf(vbn[0] + EPSV);
    float ga1 = gbn[1], be1 = bbn[1], mu1 = mbn[1], rs1 = rsqrtf(vbn[1] + EPSV);
    const float* ib = in + (size_t)b * NPTS * FTOT;
    for (int j = t; j < NPTS; j += 512) {
        float2 raw = *(const float2*)(ib + (size_t)j * FTOT);   // cols 0,1; 24B stride -> 8B aligned
        spos[j] = make_float2((raw.x - mu0) * rs0 * ga0 + be0,
                              (raw.y - mu1) * rs1 * ga1 + be1);
    }
    __syncthreads();

    int lq = t >> 5;          // local query 0..15
    int p  = t & 31;          // partition lane 0..31
    int qq = q0 + lq;
    float2 q = spos[qq];

    // ---- pass 1: per-lane lexicographic-min u64 key, 4 independent accumulators ----
    unsigned long long bm0 = ~0ULL, bm1 = ~0ULL, bm2 = ~0ULL, bm3 = ~0ULL;
    for (int jj = 0; jj < NPTS / 32; jj += 4) {
        int j0 = ((jj + 0) << 5) + p;
        int j1 = ((jj + 1) << 5) + p;
        int j2 = ((jj + 2) << 5) + p;
        int j3 = ((jj + 3) << 5) + p;
        float2 p0 = spos[j0], p1 = spos[j1], p2 = spos[j2], p3 = spos[j3];
        float d0 = __fadd_rn(__fmul_rn(q.x - p0.x, q.x - p0.x), __fmul_rn(q.y - p0.y, q.y - p0.y));
        float d1 = __fadd_rn(__fmul_rn(q.x - p1.x, q.x - p1.x), __fmul_rn(q.y - p1.y, q.y - p1.y));
        float d2 = __fadd_rn(__fmul_rn(q.x - p2.x, q.x - p2.x), __fmul_rn(q.y - p2.y, q.y - p2.y));
        float d3 = __fadd_rn(__fmul_rn(q.x - p3.x, q.x - p3.x), __fmul_rn(q.y - p3.y, q.y - p3.y));
        unsigned long long k0 = ((unsigned long long)__float_as_uint(d0) << 32) | (unsigned)j0;
        unsigned long long k1 = ((unsigned long long)__float_as_uint(d1) << 32) | (unsigned)j1;
        unsigned long long k2 = ((unsigned long long)__float_as_uint(d2) << 32) | (unsigned)j2;
        unsigned long long k3 = ((unsigned long long)__float_as_uint(d3) << 32) | (unsigned)j3;
        bm0 = k0 < bm0 ? k0 : bm0;
        bm1 = k1 < bm1 ? k1 : bm1;
        bm2 = k2 < bm2 ? k2 : bm2;
        bm3 = k3 < bm3 ? k3 : bm3;
    }
    unsigned long long bma = bm0 < bm1 ? bm0 : bm1;
    unsigned long long bmb = bm2 < bm3 ? bm2 : bm3;
    unsigned long long bm  = bma < bmb ? bma : bmb;

    // ---- threshold r = 9th smallest of the 32 lane-min keys ----
    unsigned long long KK = bm, r = 0;
#pragma unroll
    for (int rd = 0; rd < 9; ++rd) {
        unsigned long long mn = KK;
        MERGE_MIN_U64_32()
        if (KK == mn) KK = ~0ULL;   // owner retires (keys unique)
        r = mn;
    }
    unsigned long long sent = r + 1;  // keys unique: key <= r  <=>  key < sent

    // ---- pass 2: per-lane top-9 insertion, single-level if (required structure) ----
    unsigned long long K[9];
#pragma unroll
    for (int m = 0; m < 9; ++m) K[m] = sent;

#pragma unroll 4
    for (int jj = 0; jj < NPTS / 32; ++jj) {
        int j = (jj << 5) + p;
        float2 pt = spos[j];
        float dx = q.x - pt.x;
        float dy = q.y - pt.y;
        float d2 = __fadd_rn(__fmul_rn(dx, dx), __fmul_rn(dy, dy));  // no FMA contraction
        unsigned long long key = ((unsigned long long)__float_as_uint(d2) << 32) | (unsigned)j;
        if (key < K[8]) {
            K[8] = key;
#pragma unroll
            for (int m = 8; m > 0; --m) {
                bool sw = K[m] < K[m - 1];
                unsigned long long a = sw ? K[m - 1] : K[m];
                unsigned long long c = sw ? K[m] : K[m - 1];
                K[m] = a; K[m - 1] = c;
            }
        }
    }

    // ---- 9 extraction rounds: global min over the 32-lane group (>=9 real keys < sent) ----
    int rec = qq;   // inert when correct; keeps downstream in-range if not
#pragma unroll
    for (int rd = 0; rd < 9; ++rd) {
        unsigned long long mn = K[0];
        MERGE_MIN_U64_32()
        if (K[0] == mn) {   // this lane owned the min: advance its sorted list
#pragma unroll
            for (int i = 0; i < 8; ++i) K[i] = K[i + 1];
            K[8] = ~0ULL;
        }
        if (rd >= 1 && p == rd - 1) rec = (int)(unsigned)mn;   // rounds 1..8 = the 8 neighbors
    }
    rec &= (NPTS - 1);   // hard-mask to [0,4096): downstream gathers can never fault
    if (p < 8)
        idx[((size_t)b * NPTS + qq) * KNN + p] = rec;
}

// ---------------- gravnet1 v3: 4 lanes/point, bn1 applied inline per gathered feature
// (same expression order as the old k_bn1; k-ascending sums preserved) ----------------
__global__ __launch_bounds__(256) void k_g1(const float* __restrict__ in,
                                            const int* __restrict__ idx,
                                            const float* __restrict__ gbn,
                                            const float* __restrict__ bbn,
                                            const float* __restrict__ mbn,
                                            const float* __restrict__ vbn,
                                            const float* __restrict__ w1,
                                            const float* __restrict__ b1,
                                            const float* __restrict__ w2,
                                            const float* __restrict__ b2,
                                            float* __restrict__ xcat) {
    __shared__ float sw1[4 * 33], sw2[32 * 33], sb1[32], sb2[32];
    int t = threadIdx.x;
    if (t < 128) sw1[(t >> 5) * 33 + (t & 31)] = w1[t];
    for (int u = t; u < 1024; u += 256) sw2[(u >> 5) * 33 + (u & 31)] = w2[u];
    if (t < 32) { sb1[t] = b1[t]; sb2[t] = b2[t]; }
    __syncthreads();

    int i = blockIdx.x * 64 + (t >> 2);   // point
    int s = t & 3;                        // sublane
    int qb = (t & 63) & ~3;               // quad base lane within wave
    int b = i >> 12;
    int n = i & (NPTS - 1);
    const float* ib = in + (size_t)b * NPTS * FTOT;

    // bn1 params for this lane's feature column (2+s)
    float gaF = gbn[2 + s], beF = bbn[2 + s], muF = mbn[2 + s], rsF = rsqrtf(vbn[2 + s] + EPSV);

    float aggs = 0.f;
#pragma unroll
    for (int k = 0; k < KNN; ++k) {
        int nb = idx[(size_t)i * KNN + k];
        float raw = ib[(size_t)nb * FTOT + 2 + s];
        aggs += (raw - muF) * rsF * gaF + beF;   // same expr order as old k_bn1
    }
    aggs *= 0.125f;

    float af0 = __shfl(aggs, qb + 0);
    float af1 = __shfl(aggs, qb + 1);
    float af2 = __shfl(aggs, qb + 2);
    float af3 = __shfl(aggs, qb + 3);

    int o0 = 8 * s;
    float h[8];
#pragma unroll
    for (int u = 0; u < 8; ++u) {
        int o = o0 + u;
        float a = af0 * sw1[0 * 33 + o] + af1 * sw1[1 * 33 + o]
                + af2 * sw1[2 * 33 + o] + af3 * sw1[3 * 33 + o];
        h[u] = fmaxf(a + sb1[o], 0.f);
    }

    float hf[32];
#pragma unroll
    for (int w = 0; w < 4; ++w)
#pragma unroll
        for (int u = 0; u < 8; ++u)
            hf[8 * w + u] = __shfl(h[u], qb + w);

    float* oc = xcat + (size_t)i * 68;
    if (s == 0) {
        float ga0 = gbn[0], be0 = bbn[0], mu0 = mbn[0], rs0 = rsqrtf(vbn[0] + EPSV);
        float ga1 = gbn[1], be1 = bbn[1], mu1 = mbn[1], rs1 = rsqrtf(vbn[1] + EPSV);
        float2 raw = *(const float2*)(ib + (size_t)n * FTOT);
        oc[0] = (raw.x - mu0) * rs0 * ga0 + be0;
        oc[1] = (raw.y - mu1) * rs1 * ga1 + be1;
    }
#pragma unroll
    for (int u = 0; u < 8; ++u) {
        int o = o0 + u;
        float a = 0.f;
#pragma unroll
        for (int k = 0; k < 32; ++k) a += hf[k] * sw2[k * 33 + o];
        oc[2 + o] = a + sb2[o];
    }
}

// ---------------- FUSED g2 + mlp: identical to round 16/18 (passed) ----------------
__global__ __launch_bounds__(256) void k_g2m(const float* __restrict__ xcat,
                                             const int* __restrict__ idx,
                                             const float* __restrict__ gw1, const float* __restrict__ gb1,
                                             const float* __restrict__ gw2, const float* __restrict__ gb2,
                                             const float* __restrict__ w1, const float* __restrict__ b1,
                                             const float* __restrict__ w2, const float* __restrict__ b2,
                                             const float* __restrict__ w3, const float* __restrict__ b3,
                                             const float* __restrict__ g,  const float* __restrict__ be,
                                             const float* __restrict__ mn, const float* __restrict__ vr,
                                             const float* __restrict__ ow, const float* __restrict__ ob,
                                             float* __restrict__ out) {
    __shared__ float sw1[32 * 33], sw2[32 * 33], sb1[32], sb2[32];
    __shared__ float xT[68][36];
    __shared__ float h1T[128][36];
    __shared__ float h2T[64][36];
    int t = threadIdx.x;
    int base = blockIdx.x * 32;

    for (int u = t; u < 1024; u += 256) {
        sw1[(u >> 5) * 33 + (u & 31)] = gw1[u];
        sw2[(u >> 5) * 33 + (u & 31)] = gw2[u];
    }
    if (t < 32) { sb1[t] = gb1[t]; sb2[t] = gb2[t]; }
    for (int u = t; u < 32 * 34; u += 256) {
        int p = u / 34, k = u - p * 34;
        xT[k][p] = xcat[(size_t)(base + p) * 68 + k];
    }
    __syncthreads();

    if (t < 128) {
        int pt = t >> 2;
        int s  = t & 3;
        int qb = (t & 63) & ~3;
        int i  = base + pt;
        int b  = i >> 12;

        float agg[8];
#pragma unroll
        for (int u = 0; u < 8; ++u) agg[u] = 0.f;
#pragma unroll
        for (int k = 0; k < KNN; ++k) {
            int nb = idx[(size_t)i * KNN + k];
            const float2* f2 = (const float2*)(xcat + ((size_t)b * NPTS + nb) * 68 + 2 + 8 * s);
#pragma unroll
            for (int w = 0; w < 4; ++w) {
                float2 a = f2[w];
                agg[2 * w]     += a.x;
                agg[2 * w + 1] += a.y;
            }
        }
#pragma unroll
        for (int u = 0; u < 8; ++u) agg[u] *= 0.125f;

        float af[32];
#pragma unroll
        for (int w = 0; w < 4; ++w)
#pragma unroll
            for (int u = 0; u < 8; ++u)
                af[8 * w + u] = __shfl(agg[u], qb + w);

        int o0 = 8 * s;
        float h[8];
#pragma unroll
        for (int u = 0; u < 8; ++u) {
            int o = o0 + u;
            float a = 0.f;
#pragma unroll
            for (int k = 0; k < 32; ++k) a += af[k] * sw1[k * 33 + o];
            h[u] = fmaxf(a + sb1[o], 0.f);
        }

        float hf[32];
#pragma unroll
        for (int w = 0; w < 4; ++w)
#pragma unroll
            for (int u = 0; u < 8; ++u)
                hf[8 * w + u] = __shfl(h[u], qb + w);

        if (s == 0) {
            xT[34][pt] = xT[0][pt];
            xT[35][pt] = xT[1][pt];
        }
#pragma unroll
        for (int u = 0; u < 8; ++u) {
            int o = o0 + u;
            float a = 0.f;
#pragma unroll
            for (int k = 0; k < 32; ++k) a += hf[k] * sw2[k * 33 + o];
            xT[36 + o][pt] = a + sb2[o];
        }
    }
    __syncthreads();

    int pq = t & 7;
    int oq = t >> 3;

    {
        float4 bb = *(const float4*)(b1 + 4 * oq);
        float4 a0 = make_float4(bb.x, bb.x, bb.x, bb.x);
        float4 a1 = make_float4(bb.y, bb.y, bb.y, bb.y);
        float4 a2 = make_float4(bb.z, bb.z, bb.z, bb.z);
        float4 a3 = make_float4(bb.w, bb.w, bb.w, bb.w);
#pragma unroll 4
        for (int k = 0; k < 68; ++k) {
            float4 xv = *(const float4*)&xT[k][4 * pq];
            float4 wv = *(const float4*)(w1 + (size_t)k * 128 + 4 * oq);
            a0.x += wv.x * xv.x; a0.y += wv.x * xv.y; a0.z += wv.x * xv.z; a0.w += wv.x * xv.w;
            a1.x += wv.y * xv.x; a1.y += wv.y * xv.y; a1.z += wv.y * xv.z; a1.w += wv.y * xv.w;
            a2.x += wv.z * xv.x; a2.y += wv.z * xv.y; a2.z += wv.z * xv.z; a2.w += wv.z * xv.w;
            a3.x += wv.w * xv.x; a3.y += wv.w * xv.y; a3.z += wv.w * xv.z; a3.w += wv.w * xv.w;
        }
        a0.x = fmaxf(a0.x, 0.f); a0.y = fmaxf(a0.y, 0.f); a0.z = fmaxf(a0.z, 0.f); a0.w = fmaxf(a0.w, 0.f);
        a1.x = fmaxf(a1.x, 0.f); a1.y = fmaxf(a1.y, 0.f); a1.z = fmaxf(a1.z, 0.f); a1.w = fmaxf(a1.w, 0.f);
        a2.x = fmaxf(a2.x, 0.f); a2.y = fmaxf(a2.y, 0.f); a2.z = fmaxf(a2.z, 0.f); a2.w = fmaxf(a2.w, 0.f);
        a3.x = fmaxf(a3.x, 0.f); a3.y = fmaxf(a3.y, 0.f); a3.z = fmaxf(a3.z, 0.f); a3.w = fmaxf(a3.w, 0.f);
        *(float4*)&h1T[4 * oq + 0][4 * pq] = a0;
        *(float4*)&h1T[4 * oq + 1][4 * pq] = a1;
        *(float4*)&h1T[4 * oq + 2][4 * pq] = a2;
        *(float4*)&h1T[4 * oq + 3][4 * pq] = a3;
    }
    __syncthreads();

    if (t < 128) {
        float4 bb = *(const float4*)(b2 + 4 * oq);
        float4 a0 = make_float4(bb.x, bb.x, bb.x, bb.x);
        float4 a1 = make_float4(bb.y, bb.y, bb.y, bb.y);
        float4 a2 = make_float4(bb.z, bb.z, bb.z, bb.z);
        float4 a3 = make_float4(bb.w, bb.w, bb.w, bb.w);
#pragma unroll 4
        for (int k = 0; k < 128; ++k) {
            float4 xv = *(const float4*)&h1T[k][4 * pq];
            float4 wv = *(const float4*)(w2 + (size_t)k * 64 + 4 * oq);
            a0.x += wv.x * xv.x; a0.y += wv.x * xv.y; a0.z += wv.x * xv.z; a0.w += wv.x * xv.w;
            a1.x += wv.y * xv.x; a1.y += wv.y * xv.y; a1.z += wv.y * xv.z; a1.w += wv.y * xv.w;
            a2.x += wv.z * xv.x; a2.y += wv.z * xv.y; a2.z += wv.z * xv.z; a2.w += wv.z * xv.w;
            a3.x += wv.w * xv.x; a3.y += wv.w * xv.y; a3.z += wv.w * xv.z; a3.w += wv.w * xv.w;
        }
        a0.x = fmaxf(a0.x, 0.f); a0.y = fmaxf(a0.y, 0.f); a0.z = fmaxf(a0.z, 0.f); a0.w = fmaxf(a0.w, 0.f);
        a1.x = fmaxf(a1.x, 0.f); a1.y = fmaxf(a1.y, 0.f); a1.z = fmaxf(a1.z, 0.f); a1.w = fmaxf(a1.w, 0.f);
        a2.x = fmaxf(a2.x, 0.f); a2.y = fmaxf(a2.y, 0.f); a2.z = fmaxf(a2.z, 0.f); a2.w = fmaxf(a2.w, 0.f);
        a3.x = fmaxf(a3.x, 0.f); a3.y = fmaxf(a3.y, 0.f); a3.z = fmaxf(a3.z, 0.f); a3.w = fmaxf(a3.w, 0.f);
        *(float4*)&h2T[4 * oq + 0][4 * pq] = a0;
        *(float4*)&h2T[4 * oq + 1][4 * pq] = a1;
        *(float4*)&h2T[4 * oq + 2][4 * pq] = a2;
        *(float4*)&h2T[4 * oq + 3][4 * pq] = a3;
    }
    __syncthreads();

    if (t < 64) {
        float4 bb = *(const float4*)(b3 + 4 * oq);
        float4 a0 = make_float4(bb.x, bb.x, bb.x, bb.x);
        float4 a1 = make_float4(bb.y, bb.y, bb.y, bb.y);
        float4 a2 = make_float4(bb.z, bb.z, bb.z, bb.z);
        float4 a3 = make_float4(bb.w, bb.w, bb.w, bb.w);
#pragma unroll 4
        for (int k = 0; k < 64; ++k) {
            float4 xv = *(const float4*)&h2T[k][4 * pq];
            float4 wv = *(const float4*)(w3 + (size_t)k * 32 + 4 * oq);
            a0.x += wv.x * xv.x; a0.y += wv.x * xv.y; a0.z += wv.x * xv.z; a0.w += wv.x * xv.w;
            a1.x += wv.y * xv.x; a1.y += wv.y * xv.y; a1.z += wv.y * xv.z; a1.w += wv.y * xv.w;
            a2.x += wv.z * xv.x; a2.y += wv.z * xv.y; a2.z += wv.z * xv.z; a2.w += wv.z * xv.w;
            a3.x += wv.w * xv.x; a3.y += wv.w * xv.y; a3.z += wv.w * xv.z; a3.w += wv.w * xv.w;
        }
        a0.x = fmaxf(a0.x, 0.f); a0.y = fmaxf(a0.y, 0.f); a0.z = fmaxf(a0.z, 0.f); a0.w = fmaxf(a0.w, 0.f);
        a1.x = fmaxf(a1.x, 0.f); a1.y = fmaxf(a1.y, 0.f); a1.z = fmaxf(a1.z, 0.f); a1.w = fmaxf(a1.w, 0.f);
        a2.x = fmaxf(a2.x, 0.f); a2.y = fmaxf(a2.y, 0.f); a2.z = fmaxf(a2.z, 0.f); a2.w = fmaxf(a2.w, 0.f);
        a3.x = fmaxf(a3.x, 0.f); a3.y = fmaxf(a3.y, 0.f); a3.z = fmaxf(a3.z, 0.f); a3.w = fmaxf(a3.w, 0.f);
        int c0 = 4 * oq;
        float s0 = g[c0 + 0] * rsqrtf(vr[c0 + 0] + EPSV);
        float s1 = g[c0 + 1] * rsqrtf(vr[c0 + 1] + EPSV);
        float s2 = g[c0 + 2] * rsqrtf(vr[c0 + 2] + EPSV);
        float s3 = g[c0 + 3] * rsqrtf(vr[c0 + 3] + EPSV);
        float w0 = s0 * ow[c0 + 0], w1c = s1 * ow[c0 + 1];
        float w2c = s2 * ow[c0 + 2], w3c = s3 * ow[c0 + 3];
        float tt = (be[c0 + 0] - mn[c0 + 0] * s0) * ow[c0 + 0]
                 + (be[c0 + 1] - mn[c0 + 1] * s1) * ow[c0 + 1]
                 + (be[c0 + 2] - mn[c0 + 2] * s2) * ow[c0 + 2]
                 + (be[c0 + 3] - mn[c0 + 3] * s3) * ow[c0 + 3];
        float4 s;
        s.x = a0.x * w0 + a1.x * w1c + a2.x * w2c + a3.x * w3c;
        s.y = a0.y * w0 + a1.y * w1c + a2.y * w2c + a3.y * w3c;
        s.z = a0.z * w0 + a1.z * w1c + a2.z * w2c + a3.z * w3c;
        s.w = a0.w * w0 + a1.w * w1c + a2.w * w2c + a3.w * w3c;
#pragma unroll
        for (int msk = 8; msk <= 32; msk <<= 1) {
            s.x += __shfl_xor(s.x, msk);
            s.y += __shfl_xor(s.y, msk);
            s.z += __shfl_xor(s.z, msk);
            s.w += __shfl_xor(s.w, msk);
            tt  += __shfl_xor(tt,  msk);
        }
        if (oq == 0) {
            float c = tt + ob[0];
            *(float4*)(out + base + 4 * pq) = make_float4(s.x + c, s.y + c, s.z + c, s.w + c);
        }
    }
}

extern "C" void kernel_launch(void* const* d_in, const int* in_sizes, int n_in,
                              void* d_out, int out_size, void* d_ws, size_t ws_size,
                              hipStream_t stream) {
    const float* inputs    = (const float*)d_in[0];
    const float* bn1_gamma = (const float*)d_in[1];
    const float* bn1_beta  = (const float*)d_in[2];
    const float* bn1_mean  = (const float*)d_in[3];
    const float* bn1_var   = (const float*)d_in[4];
    const float* g1_w1 = (const float*)d_in[5];
    const float* g1_b1 = (const float*)d_in[6];
    const float* g1_w2 = (const float*)d_in[7];
    const float* g1_b2 = (const float*)d_in[8];
    const float* g2_w1 = (const float*)d_in[9];
    const float* g2_b1 = (const float*)d_in[10];
    const float* g2_w2 = (const float*)d_in[11];
    const float* g2_b2 = (const float*)d_in[12];
    const float* d1_w = (const float*)d_in[13];
    const float* d1_b = (const float*)d_in[14];
    const float* d2_w = (const float*)d_in[15];
    const float* d2_b = (const float*)d_in[16];
    const float* d3_w = (const float*)d_in[17];
    const float* d3_b = (const float*)d_in[18];
    const float* bn2_gamma = (const float*)d_in[19];
    const float* bn2_beta  = (const float*)d_in[20];
    const float* bn2_mean  = (const float*)d_in[21];
    const float* bn2_var   = (const float*)d_in[22];
    const float* out_w = (const float*)d_in[23];
    const float* out_b = (const float*)d_in[24];
    float* out = (float*)d_out;

    const size_t BN = (size_t)BTOT * NPTS;
    char* ws = (char*)d_ws;
    size_t off = 0;
    auto alloc = [&](size_t bytes) { char* p = ws + off; off += (bytes + 255) & ~(size_t)255; return p; };
    int*   idx  = (int*)  alloc(BN * KNN * sizeof(int));
    float* xcat = (float*)alloc(BN * 68  * sizeof(float));   // only cols [0,34) live in global
    (void)ws_size; (void)n_in; (void)in_sizes; (void)out_size;

    k_knn<<<dim3(1024), dim3(512), 0, stream>>>(inputs, bn1_gamma, bn1_beta, bn1_mean, bn1_var, idx);
    k_g1 <<<dim3(256),  dim3(256), 0, stream>>>(inputs, idx, bn1_gamma, bn1_beta, bn1_mean, bn1_var,
                                                g1_w1, g1_b1, g1_w2, g1_b2, xcat);
    k_g2m<<<dim3(512),  dim3(256), 0, stream>>>(xcat, idx,
                                                g2_w1, g2_b1, g2_w2, g2_b2,
                                                d1_w, d1_b, d2_w, d2_b, d3_w, d3_b,
                                                bn2_gamma, bn2_beta, bn2_mean, bn2_var,
                                                out_w, out_b, out);
}